// Round 7
// baseline (2901.769 us; speedup 1.0000x reference)
//
#include <hip/hip_runtime.h>
#include <hip/hip_cooperative_groups.h>

namespace cg = cooperative_groups;

typedef unsigned int uint;
typedef unsigned short ushort;

typedef short short8 __attribute__((ext_vector_type(8)));
typedef float floatx4 __attribute__((ext_vector_type(4)));
typedef uint uintx4 __attribute__((ext_vector_type(4)));

#define FIN 512
#define HF  128
#define NC  40
#define KHOPS 10

__device__ __forceinline__ ushort f2bf(float f) {
    uint u = __float_as_uint(f);
    uint r = (u + 0x7fffu + ((u >> 16) & 1u)) >> 16;
    return (ushort)r;
}
__device__ __forceinline__ float bflo(uint v) { return __uint_as_float(v << 16); }
__device__ __forceinline__ float bfhi(uint v) { return __uint_as_float(v & 0xffff0000u); }
__device__ __forceinline__ uint packbf2(float a, float b) {
    return (uint)f2bf(a) | ((uint)f2bf(b) << 16);
}
__device__ __forceinline__ uint cvtpk(float lo, float hi) {
    uint r;
    asm("v_cvt_pk_bf16_f32 %0, %1, %2" : "=v"(r) : "v"(lo), "v"(hi));
    return r;
}
__device__ __forceinline__ float selu_f(float v) {
    const float l = 1.0507009873554805f, a = 1.6732632423543772f;
    return v > 0.f ? l * v : l * a * (expf(v) - 1.f);
}

#define GLDS16(g, l)                                                        \
    __builtin_amdgcn_global_load_lds(                                       \
        (const __attribute__((address_space(1))) void*)(g),                 \
        (__attribute__((address_space(3))) void*)(l), 16, 0, 0)

// ---------------- W1 -> MFMA fragment layout (bf16) ----------------
__global__ void k_w1frag(const float* __restrict__ W1, ushort* __restrict__ w1f) {
    int id = blockIdx.x * 256 + threadIdx.x;
    if (id >= 16 * 8 * 64) return;
    int l = id & 63;
    int t = (id >> 6) & 7;
    int s = id >> 9;
    int row0 = s * 32 + (l >> 4) * 8;
    int col  = t * 16 + (l & 15);
    ushort* dst = w1f + (size_t)id * 8;
#pragma unroll
    for (int i = 0; i < 8; ++i)
        dst[i] = f2bf(W1[(row0 + i) * HF + col]);
}

// ---------------- W2 -> MFMA fragment layout (bf16, 48-col padded) ----------------
__global__ void k_w2frag(const float* __restrict__ W2, ushort* __restrict__ w2f) {
    int id = blockIdx.x * 256 + threadIdx.x;
    if (id >= 12 * 64) return;
    int l = id & 63;
    int tile = id >> 6;
    int kk = tile / 3, t = tile % 3;
    int row0 = kk * 32 + (l >> 4) * 8;
    int col  = t * 16 + (l & 15);
    ushort* dst = w2f + (size_t)id * 8;
#pragma unroll
    for (int i = 0; i < 8; ++i)
        dst[i] = (col < NC) ? f2bf(W2[(row0 + i) * NC + col]) : (ushort)0;
}

// ---------------- h = selu(x@W1+b1) -> hops[0] (bf16), fused fp0 + msum[0] ----
__global__ __launch_bounds__(256) void k_gemm(
        const float* __restrict__ x, const ushort* __restrict__ w1f,
        const float* __restrict__ b1, ushort* __restrict__ h,
        const float* __restrict__ projw, const float* __restrict__ projb,
        float* __restrict__ fp0, float* __restrict__ msum, int N) {
    __shared__ __align__(16) float bufA[4][32 * 32];
    __shared__ __align__(16) float bufB[4][32 * 32];
    int tid = threadIdx.x;
    int lane = tid & 63, w = tid >> 6;
    int rowblk = blockIdx.x * 128 + w * 32;

    int srl = lane >> 3;
    int ssl = lane & 7;
    int srcoff = ((ssl ^ srl) << 2);
    float* bA = bufA[w];
    float* bB = bufB[w];

    floatx4 acc[2][8];
#pragma unroll
    for (int rt = 0; rt < 2; ++rt)
#pragma unroll
        for (int t = 0; t < 8; ++t) acc[rt][t] = (floatx4){0.f, 0.f, 0.f, 0.f};

    short8 bE[8], bO[8];

    auto STAGE = [&](float* lbuf, int kk) {
        int k0 = kk * 32;
#pragma unroll
        for (int i = 0; i < 4; ++i) {
            int row = rowblk + i * 8 + srl;
            const float* g = x + (size_t)min(row, N - 1) * FIN + k0 + srcoff;
            GLDS16(g, lbuf + i * 256);
        }
    };
    auto LOADB = [&](short8* bb, int kk) {
        const ushort* wp = w1f + ((size_t)(kk * 8) * 64 + lane) * 8;
#pragma unroll
        for (int t = 0; t < 8; ++t) bb[t] = *(const short8*)(wp + (size_t)t * 512);
    };

    int rl16 = lane & 15, cq = lane >> 4;
    int lo_sl = ((2 * cq) ^ (rl16 & 7)) << 4;
    int hi_sl = ((2 * cq + 1) ^ (rl16 & 7)) << 4;

    auto COMPUTE = [&](const float* lbuf, short8* bb) {
#pragma unroll
        for (int rt = 0; rt < 2; ++rt) {
            const char* rbase = (const char*)lbuf + (rt * 16 + rl16) * 128;
            float4 lo = *(const float4*)(rbase + lo_sl);
            float4 hi = *(const float4*)(rbase + hi_sl);
            uintx4 pa;
            pa.x = cvtpk(lo.x, lo.y); pa.y = cvtpk(lo.z, lo.w);
            pa.z = cvtpk(hi.x, hi.y); pa.w = cvtpk(hi.z, hi.w);
            short8 af = __builtin_bit_cast(short8, pa);
#pragma unroll
            for (int t = 0; t < 8; ++t)
                acc[rt][t] = __builtin_amdgcn_mfma_f32_16x16x32_bf16(af, bb[t], acc[rt][t], 0, 0, 0);
        }
    };

    STAGE(bA, 0);
    LOADB(bE, 0);
#pragma unroll 1
    for (int kk = 0; kk < 16; kk += 2) {
        asm volatile("s_waitcnt lgkmcnt(0)" ::: "memory");
        __builtin_amdgcn_sched_barrier(0);
        STAGE(bB, kk + 1);
        LOADB(bO, kk + 1);
        asm volatile("s_waitcnt vmcnt(12)" ::: "memory");
        __builtin_amdgcn_sched_barrier(0);
        COMPUTE(bA, bE);
        asm volatile("s_waitcnt lgkmcnt(0)" ::: "memory");
        __builtin_amdgcn_sched_barrier(0);
        if (kk + 2 < 16) {
            STAGE(bA, kk + 2);
            LOADB(bE, kk + 2);
            asm volatile("s_waitcnt vmcnt(12)" ::: "memory");
        } else {
            asm volatile("s_waitcnt vmcnt(0)" ::: "memory");
        }
        __builtin_amdgcn_sched_barrier(0);
        COMPUTE(bB, bO);
    }

    // epilogue: selu + store bf16 + fused fp0 (dot with projw)
    int col0 = lane & 15;
    float fpd[2][4];
#pragma unroll
    for (int rt = 0; rt < 2; ++rt)
#pragma unroll
        for (int q = 0; q < 4; ++q) fpd[rt][q] = 0.f;
#pragma unroll
    for (int t = 0; t < 8; ++t) {
        int col = t * 16 + col0;
        float bias = b1[col];
        float pw = projw[col];
#pragma unroll
        for (int rt = 0; rt < 2; ++rt) {
#pragma unroll
            for (int q = 0; q < 4; ++q) {
                int row = rowblk + rt * 16 + (lane >> 4) * 4 + q;
                float v = selu_f(acc[rt][t][q] + bias);
                if (row < N) h[(size_t)row * HF + col] = f2bf(v);
                fpd[rt][q] = fmaf(v, pw, fpd[rt][q]);
            }
        }
    }
#pragma unroll
    for (int rt = 0; rt < 2; ++rt)
#pragma unroll
        for (int q = 0; q < 4; ++q) {
            float d = fpd[rt][q];
#pragma unroll
            for (int m = 1; m < 16; m <<= 1) d += __shfl_xor(d, m);
            fpd[rt][q] = d;
        }
    float s0 = 0.f;
    if (col0 == 0) {
        float pb = projb[0];
#pragma unroll
        for (int rt = 0; rt < 2; ++rt)
#pragma unroll
            for (int q = 0; q < 4; ++q) {
                int row = rowblk + rt * 16 + (lane >> 4) * 4 + q;
                if (row < N) {
                    fp0[row] = fpd[rt][q] + pb;
                    s0 += fpd[rt][q];   // pb added once per node in k_sharew
                }
            }
    }
    // reduce s0 across lanes 0/16/32/48 (others are 0), then block reduce
    s0 += __shfl_xor(s0, 16);
    s0 += __shfl_xor(s0, 32);
    if (lane == 0) bufA[w][0] = s0;
    __syncthreads();
    if (tid == 0) atomicAdd(msum, bufA[0][0] + bufA[1][0] + bufA[2][0] + bufA[3][0]);
}

// ---------------- degree (real edges only; self handled as +1) ----------------
__global__ void k_deg(const int* __restrict__ ei, int* __restrict__ deg, int E) {
    int e = blockIdx.x * 256 + threadIdx.x;
    if (e < E) atomicAdd(&deg[ei[E + e]], 1);
}

// ---------------- exclusive scan of deg -> offsets, fused dinv ----------------
__global__ void k_scan1(const int* __restrict__ deg, int* __restrict__ offs,
                        int* __restrict__ bsum, float* __restrict__ dinv, int N) {
    __shared__ int lds[256];
    int tid = threadIdx.x;
    int base = blockIdx.x * 1024;
    int c[4], s = 0;
#pragma unroll
    for (int i = 0; i < 4; ++i) {
        int g = base + tid * 4 + i;
        int dv = (g < N) ? deg[g] : 0;
        if (g < N) dinv[g] = rsqrtf((float)(dv + 1));
        c[i] = dv;
        s += dv;
    }
    lds[tid] = s;
    __syncthreads();
    for (int off = 1; off < 256; off <<= 1) {
        int add = (tid >= off) ? lds[tid - off] : 0;
        __syncthreads();
        lds[tid] += add;
        __syncthreads();
    }
    int run = lds[tid] - s;
#pragma unroll
    for (int i = 0; i < 4; ++i) {
        int g = base + tid * 4 + i;
        if (g < N) offs[g] = run;
        run += c[i];
    }
    if (tid == 0) bsum[blockIdx.x] = lds[255];
}
__global__ void k_scan2(int* __restrict__ bsum, int nb) {
    if (blockIdx.x == 0 && threadIdx.x == 0) {
        int run = 0;
        for (int i = 0; i < nb; ++i) { int v = bsum[i]; bsum[i] = run; run += v; }
    }
}
__global__ void k_scan3(int* __restrict__ offs, const int* __restrict__ bsum, int N, int E) {
    int g = blockIdx.x * 256 + threadIdx.x;
    if (g < N) offs[g] += bsum[g >> 10];
    else if (g == N) offs[N] = E;
}

// ---------------- CSR fill: edat = {src, bits(dinv_r*dinv_c)} ----------------
__global__ void k_fill(const int* __restrict__ ei, const int* __restrict__ offs,
                       int* __restrict__ cursor, int2* __restrict__ edat,
                       const float* __restrict__ dinv, int E) {
    int e = blockIdx.x * 256 + threadIdx.x;
    if (e >= E) return;
    int r = ei[e], c = ei[E + e];
    int p = offs[c] + atomicAdd(&cursor[c], 1);
    edat[p] = make_int2(r, __float_as_int(dinv[r] * dinv[c]));
}

// ---------------- ALL K hops: persistent cooperative kernel ----------------
__global__ __launch_bounds__(256, 4) void k_hops(
        ushort* __restrict__ hops, const int* __restrict__ offs,
        const int2* __restrict__ edat, const float* __restrict__ dinv,
        const float* __restrict__ projw, const float* __restrict__ projb,
        float* __restrict__ fp, float* __restrict__ msum, int N) {
    cg::grid_group grid = cg::this_grid();
    __shared__ float bms[4];
    int tid = threadIdx.x;
    int lane = tid & 63, w = tid >> 6;
    int gwid = blockIdx.x * 4 + w;
    int nw = gridDim.x * 4;
    float pw0 = projw[2 * lane], pw1 = projw[2 * lane + 1];
    float pb = projb[0];

    for (int k = 1; k <= KHOPS; ++k) {
        const uint* xin2 = (const uint*)(hops + (size_t)(k - 1) * N * HF);
        uint* xo = (uint*)(hops + (size_t)k * N * HF);
        float* fpk = fp + (size_t)k * N;
        float ms = 0.f;
        for (int wid = gwid; wid < N; wid += nw) {
            float dn = dinv[wid];
            uint sv = xin2[(size_t)wid * 64 + lane];
            float wself = dn * dn;
            float acc0 = wself * bflo(sv);
            float acc1 = wself * bfhi(sv);
            int s = offs[wid], e = offs[wid + 1];
            for (int base = s; base < e; base += 64) {
                int idx = base + lane;
                int idxc = min(idx, e - 1);
                int2 ed = edat[idxc];
                int src = ed.x;
                float ew = (idx < e) ? __int_as_float(ed.y) : 0.f;
                int cnt = min(64, e - base);
                int groups = (cnt + 15) >> 4;
                for (int g = 0; g < groups; ++g) {
                    int j = g * 16;
                    uint xv[16];
                    float wv[16];
#pragma unroll
                    for (int u = 0; u < 16; ++u) {
                        int sj = __builtin_amdgcn_readlane(src, j + u);
                        wv[u] = __int_as_float(__builtin_amdgcn_readlane(__float_as_int(ew), j + u));
                        xv[u] = xin2[(size_t)(uint)sj * 64 + lane];
                    }
#pragma unroll
                    for (int u = 0; u < 16; ++u) {
                        acc0 = fmaf(wv[u], bflo(xv[u]), acc0);
                        acc1 = fmaf(wv[u], bfhi(xv[u]), acc1);
                    }
                }
            }
            xo[(size_t)wid * 64 + lane] = packbf2(acc0, acc1);
            float dot = acc0 * pw0 + acc1 * pw1;
#pragma unroll
            for (int m = 1; m < 64; m <<= 1) dot += __shfl_xor(dot, m);
            dot += pb;
            if (lane == 0) { fpk[wid] = dot; ms += dot; }
        }
        if (lane == 0) bms[w] = ms;
        __syncthreads();
        if (tid == 0) atomicAdd(&msum[k], bms[0] + bms[1] + bms[2] + bms[3]);
        if (k < KHOPS) {
            __threadfence();
            grid.sync();
        }
    }
}

// ---------------- share_w = l2norm(mean + hop_w) ----------------
__global__ void k_sharew(const float* __restrict__ msum, const float* __restrict__ hopw,
                         float* __restrict__ sharew, const float* __restrict__ projb, int N) {
    int k = threadIdx.x;
    float s = 0.f;
    if (k < KHOPS + 1) {
        s = msum[k] / (float)N + hopw[k];
        if (k == 0) s += projb[0];   // msum[0] accumulated without pb
    }
    float ss = s * s;
#pragma unroll
    for (int m = 1; m < 64; m <<= 1) ss += __shfl_xor(ss, m);
    float inv = 1.f / fmaxf(sqrtf(ss), 1e-12f);
    if (k < KHOPS + 1) sharew[k] = s * inv;
}

// ---------------- k_out: 16 nodes/block; single-pass combine (16B/thread),
//                  tanh -> LDS, MFMA K=128 N=48, log_softmax ----------------
__global__ __launch_bounds__(256) void k_out(
                     const ushort* __restrict__ hops, const float* __restrict__ fp,
                     const float* __restrict__ sharew, const ushort* __restrict__ w2f,
                     const float* __restrict__ b2, float* __restrict__ out, int N) {
    __shared__ __align__(16) char As[16 * 256];
    int tid = threadIdx.x;
    int nloc = tid >> 4;
    int fg = tid & 15;
    int node = blockIdx.x * 16 + nloc;
    bool valid = node < N;
    int nodec = valid ? node : N - 1;
    const uint* hops2 = (const uint*)hops;

    float c[KHOPS + 1];
    float ss = 0.f;
#pragma unroll
    for (int k = 0; k <= KHOPS; ++k) {
        float f = fp[(size_t)k * N + nodec];
        c[k] = f;
        ss += f * f;
    }
    float inv = 1.f / fmaxf(sqrtf(ss), 1e-12f);
#pragma unroll
    for (int k = 0; k <= KHOPS; ++k)
        c[k] = valid ? (0.2f * sharew[k] + 0.8f * c[k] * inv) : 0.f;

    const uint* base = hops2 + (size_t)nodec * 64 + fg * 4;
    size_t kstr = (size_t)N * 64;
    float a[8];
#pragma unroll
    for (int j = 0; j < 8; ++j) a[j] = 0.f;
#pragma unroll
    for (int k = 0; k <= KHOPS; ++k) {
        uint4 v = *(const uint4*)(base + (size_t)k * kstr);
        float ck = c[k];
        a[0] = fmaf(ck, bflo(v.x), a[0]);
        a[1] = fmaf(ck, bfhi(v.x), a[1]);
        a[2] = fmaf(ck, bflo(v.y), a[2]);
        a[3] = fmaf(ck, bfhi(v.y), a[3]);
        a[4] = fmaf(ck, bflo(v.z), a[4]);
        a[5] = fmaf(ck, bfhi(v.z), a[5]);
        a[6] = fmaf(ck, bflo(v.w), a[6]);
        a[7] = fmaf(ck, bfhi(v.w), a[7]);
    }
    uint4 pk;
    pk.x = packbf2(tanhf(a[0]), tanhf(a[1]));
    pk.y = packbf2(tanhf(a[2]), tanhf(a[3]));
    pk.z = packbf2(tanhf(a[4]), tanhf(a[5]));
    pk.w = packbf2(tanhf(a[6]), tanhf(a[7]));
    {
        int slotbyte = fg * 16;
        int addr = nloc * 256 + (slotbyte ^ ((nloc & 15) << 4));
        *(uint4*)(As + addr) = pk;
    }
    __syncthreads();

    int w = tid >> 6, lane = tid & 63;
    floatx4 acc = (floatx4){0.f, 0.f, 0.f, 0.f};
    if (w < 3) {
        int r = lane & 15;
#pragma unroll
        for (int kk = 0; kk < 4; ++kk) {
            int slotbyte = kk * 64 + (lane >> 4) * 16;
            int addr = r * 256 + (slotbyte ^ ((r & 15) << 4));
            short8 af = *(const short8*)(As + addr);
            const short8 bf = *(const short8*)(w2f + (size_t)((kk * 3 + w) * 64 + lane) * 8);
            acc = __builtin_amdgcn_mfma_f32_16x16x32_bf16(af, bf, acc, 0, 0, 0);
        }
    }
    __syncthreads();

    float* Ls = (float*)As;
    if (w < 3) {
        int cls = w * 16 + (lane & 15);
        float bb = (cls < NC) ? b2[cls] : 0.f;
#pragma unroll
        for (int q = 0; q < 4; ++q) {
            int row = (lane >> 4) * 4 + q;
            Ls[row * 48 + cls] = acc[q] + bb;
        }
    }
    __syncthreads();

    int r2 = tid >> 4;
    int c16 = tid & 15;
    float v0 = Ls[r2 * 48 + c16];
    float v1 = Ls[r2 * 48 + 16 + c16];
    bool has2 = c16 < 8;
    float v2 = has2 ? Ls[r2 * 48 + 32 + c16] : -INFINITY;
    float lm = fmaxf(fmaxf(v0, v1), v2);
#pragma unroll
    for (int m = 1; m < 16; m <<= 1) lm = fmaxf(lm, __shfl_xor(lm, m));
    float se = expf(v0 - lm) + expf(v1 - lm) + (has2 ? expf(v2 - lm) : 0.f);
#pragma unroll
    for (int m = 1; m < 16; m <<= 1) se += __shfl_xor(se, m);
    float lse = lm + logf(se);
    int nodeo = blockIdx.x * 16 + r2;
    if (nodeo < N) {
        out[(size_t)nodeo * NC + c16] = v0 - lse;
        out[(size_t)nodeo * NC + 16 + c16] = v1 - lse;
        if (has2) out[(size_t)nodeo * NC + 32 + c16] = v2 - lse;
    }
}

// ---------------- launch ----------------
extern "C" void kernel_launch(void* const* d_in, const int* in_sizes, int n_in,
                              void* d_out, int out_size, void* d_ws, size_t ws_size,
                              hipStream_t stream) {
    const float* x     = (const float*)d_in[0];
    const int*   ei    = (const int*)d_in[1];
    const float* W1    = (const float*)d_in[2];
    const float* b1    = (const float*)d_in[3];
    const float* projw = (const float*)d_in[4];
    const float* projb = (const float*)d_in[5];
    const float* hopw  = (const float*)d_in[6];
    const float* W2    = (const float*)d_in[7];
    const float* b2    = (const float*)d_in[8];
    float* out = (float*)d_out;

    int N = in_sizes[0] / FIN;
    int E = in_sizes[1] / 2;

    char* p = (char*)d_ws;
    auto alloc = [&](size_t bytes) -> char* {
        char* r = p;
        p += (bytes + 255) & ~(size_t)255;
        return r;
    };
    ushort* hops   = (ushort*)alloc((size_t)(KHOPS + 1) * N * HF * 2);
    int*    deg    = (int*)alloc((size_t)N * 4);
    int*    cursor = (int*)alloc((size_t)N * 4);   // adjacent to deg: one memset covers both
    float*  dinv   = (float*)alloc((size_t)N * 4);
    int*    offs   = (int*)alloc((size_t)(N + 1) * 4);
    int*    bsum   = (int*)alloc(4096);
    int2*   edat   = (int2*)alloc((size_t)E * 8);
    float*  fp     = (float*)alloc((size_t)(KHOPS + 1) * N * 4);
    float*  msum   = (float*)alloc(64);
    float*  sharew = (float*)alloc(64);
    ushort* w1f    = (ushort*)alloc((size_t)FIN * HF * 2);
    ushort* w2f    = (ushort*)alloc((size_t)12 * 64 * 8 * 2);

    int nbE    = (E + 255) / 256;
    int nb1024 = (N + 1023) / 1024;

    size_t zlen = (size_t)((char*)cursor - (char*)deg) + (size_t)N * 4;
    hipMemsetAsync(deg, 0, zlen, stream);
    hipMemsetAsync(msum, 0, 64, stream);

    k_w1frag<<<32, 256, 0, stream>>>(W1, w1f);
    k_w2frag<<<3, 256, 0, stream>>>(W2, w2f);
    k_gemm<<<(N + 127) / 128, 256, 0, stream>>>(x, w1f, b1, hops, projw, projb, fp, msum, N);

    k_deg<<<nbE, 256, 0, stream>>>(ei, deg, E);
    k_scan1<<<nb1024, 256, 0, stream>>>(deg, offs, bsum, dinv, N);
    k_scan2<<<1, 64, 0, stream>>>(bsum, nb1024);
    k_scan3<<<(N + 256) / 256, 256, 0, stream>>>(offs, bsum, N, E);
    k_fill<<<nbE, 256, 0, stream>>>(ei, offs, cursor, edat, dinv, E);

    {
        void* args[] = {(void*)&hops, (void*)&offs, (void*)&edat, (void*)&dinv,
                        (void*)&projw, (void*)&projb, (void*)&fp, (void*)&msum, (void*)&N};
        hipLaunchCooperativeKernel((void*)k_hops, dim3(1024), dim3(256), args, 0, stream);
    }

    k_sharew<<<1, 64, 0, stream>>>(msum, hopw, sharew, projb, N);
    k_out<<<(N + 15) / 16, 256, 0, stream>>>(hops, fp, sharew, w2f, b2, out, N);
}

// Round 8
// 2896.165 us; speedup vs baseline: 1.0019x; 1.0019x over previous
//
#include <hip/hip_runtime.h>

typedef unsigned int uint;
typedef unsigned short ushort;

typedef short short8 __attribute__((ext_vector_type(8)));
typedef float floatx4 __attribute__((ext_vector_type(4)));
typedef uint uintx4 __attribute__((ext_vector_type(4)));

#define FIN 512
#define HF  128
#define NC  40
#define KHOPS 10
#define NWIN 8

__device__ __forceinline__ ushort f2bf(float f) {
    uint u = __float_as_uint(f);
    uint r = (u + 0x7fffu + ((u >> 16) & 1u)) >> 16;
    return (ushort)r;
}
__device__ __forceinline__ float bflo(uint v) { return __uint_as_float(v << 16); }
__device__ __forceinline__ float bfhi(uint v) { return __uint_as_float(v & 0xffff0000u); }
__device__ __forceinline__ uint packbf2(float a, float b) {
    return (uint)f2bf(a) | ((uint)f2bf(b) << 16);
}
__device__ __forceinline__ uint cvtpk(float lo, float hi) {
    uint r;
    asm("v_cvt_pk_bf16_f32 %0, %1, %2" : "=v"(r) : "v"(lo), "v"(hi));
    return r;
}
__device__ __forceinline__ float selu_f(float v) {
    const float l = 1.0507009873554805f, a = 1.6732632423543772f;
    return v > 0.f ? l * v : l * a * (expf(v) - 1.f);
}

#define GLDS16(g, l)                                                        \
    __builtin_amdgcn_global_load_lds(                                       \
        (const __attribute__((address_space(1))) void*)(g),                 \
        (__attribute__((address_space(3))) void*)(l), 16, 0, 0)

// ---------------- W1 -> MFMA fragment layout (bf16) ----------------
__global__ void k_w1frag(const float* __restrict__ W1, ushort* __restrict__ w1f) {
    int id = blockIdx.x * 256 + threadIdx.x;
    if (id >= 16 * 8 * 64) return;
    int l = id & 63;
    int t = (id >> 6) & 7;
    int s = id >> 9;
    int row0 = s * 32 + (l >> 4) * 8;
    int col  = t * 16 + (l & 15);
    ushort* dst = w1f + (size_t)id * 8;
#pragma unroll
    for (int i = 0; i < 8; ++i)
        dst[i] = f2bf(W1[(row0 + i) * HF + col]);
}

// ---------------- W2 -> MFMA fragment layout (bf16, 48-col padded) ----------------
__global__ void k_w2frag(const float* __restrict__ W2, ushort* __restrict__ w2f) {
    int id = blockIdx.x * 256 + threadIdx.x;
    if (id >= 12 * 64) return;
    int l = id & 63;
    int tile = id >> 6;
    int kk = tile / 3, t = tile % 3;
    int row0 = kk * 32 + (l >> 4) * 8;
    int col  = t * 16 + (l & 15);
    ushort* dst = w2f + (size_t)id * 8;
#pragma unroll
    for (int i = 0; i < 8; ++i)
        dst[i] = (col < NC) ? f2bf(W2[(row0 + i) * NC + col]) : (ushort)0;
}

// ---------------- h = selu(x@W1+b1) -> hops[0] (bf16), fused fp0 + msum[0] ----
__global__ __launch_bounds__(256) void k_gemm(
        const float* __restrict__ x, const ushort* __restrict__ w1f,
        const float* __restrict__ b1, ushort* __restrict__ h,
        const float* __restrict__ projw, const float* __restrict__ projb,
        float* __restrict__ fp0, float* __restrict__ msum, int N) {
    __shared__ __align__(16) float bufA[4][32 * 32];
    __shared__ __align__(16) float bufB[4][32 * 32];
    int tid = threadIdx.x;
    int lane = tid & 63, w = tid >> 6;
    int rowblk = blockIdx.x * 128 + w * 32;

    int srl = lane >> 3;
    int ssl = lane & 7;
    int srcoff = ((ssl ^ srl) << 2);
    float* bA = bufA[w];
    float* bB = bufB[w];

    floatx4 acc[2][8];
#pragma unroll
    for (int rt = 0; rt < 2; ++rt)
#pragma unroll
        for (int t = 0; t < 8; ++t) acc[rt][t] = (floatx4){0.f, 0.f, 0.f, 0.f};

    short8 bE[8], bO[8];

    auto STAGE = [&](float* lbuf, int kk) {
        int k0 = kk * 32;
#pragma unroll
        for (int i = 0; i < 4; ++i) {
            int row = rowblk + i * 8 + srl;
            const float* g = x + (size_t)min(row, N - 1) * FIN + k0 + srcoff;
            GLDS16(g, lbuf + i * 256);
        }
    };
    auto LOADB = [&](short8* bb, int kk) {
        const ushort* wp = w1f + ((size_t)(kk * 8) * 64 + lane) * 8;
#pragma unroll
        for (int t = 0; t < 8; ++t) bb[t] = *(const short8*)(wp + (size_t)t * 512);
    };

    int rl16 = lane & 15, cq = lane >> 4;
    int lo_sl = ((2 * cq) ^ (rl16 & 7)) << 4;
    int hi_sl = ((2 * cq + 1) ^ (rl16 & 7)) << 4;

    auto COMPUTE = [&](const float* lbuf, short8* bb) {
#pragma unroll
        for (int rt = 0; rt < 2; ++rt) {
            const char* rbase = (const char*)lbuf + (rt * 16 + rl16) * 128;
            float4 lo = *(const float4*)(rbase + lo_sl);
            float4 hi = *(const float4*)(rbase + hi_sl);
            uintx4 pa;
            pa.x = cvtpk(lo.x, lo.y); pa.y = cvtpk(lo.z, lo.w);
            pa.z = cvtpk(hi.x, hi.y); pa.w = cvtpk(hi.z, hi.w);
            short8 af = __builtin_bit_cast(short8, pa);
#pragma unroll
            for (int t = 0; t < 8; ++t)
                acc[rt][t] = __builtin_amdgcn_mfma_f32_16x16x32_bf16(af, bb[t], acc[rt][t], 0, 0, 0);
        }
    };

    STAGE(bA, 0);
    LOADB(bE, 0);
#pragma unroll 1
    for (int kk = 0; kk < 16; kk += 2) {
        asm volatile("s_waitcnt lgkmcnt(0)" ::: "memory");
        __builtin_amdgcn_sched_barrier(0);
        STAGE(bB, kk + 1);
        LOADB(bO, kk + 1);
        asm volatile("s_waitcnt vmcnt(12)" ::: "memory");
        __builtin_amdgcn_sched_barrier(0);
        COMPUTE(bA, bE);
        asm volatile("s_waitcnt lgkmcnt(0)" ::: "memory");
        __builtin_amdgcn_sched_barrier(0);
        if (kk + 2 < 16) {
            STAGE(bA, kk + 2);
            LOADB(bE, kk + 2);
            asm volatile("s_waitcnt vmcnt(12)" ::: "memory");
        } else {
            asm volatile("s_waitcnt vmcnt(0)" ::: "memory");
        }
        __builtin_amdgcn_sched_barrier(0);
        COMPUTE(bB, bO);
    }

    int col0 = lane & 15;
    float fpd[2][4];
#pragma unroll
    for (int rt = 0; rt < 2; ++rt)
#pragma unroll
        for (int q = 0; q < 4; ++q) fpd[rt][q] = 0.f;
#pragma unroll
    for (int t = 0; t < 8; ++t) {
        int col = t * 16 + col0;
        float bias = b1[col];
        float pw = projw[col];
#pragma unroll
        for (int rt = 0; rt < 2; ++rt) {
#pragma unroll
            for (int q = 0; q < 4; ++q) {
                int row = rowblk + rt * 16 + (lane >> 4) * 4 + q;
                float v = selu_f(acc[rt][t][q] + bias);
                if (row < N) h[(size_t)row * HF + col] = f2bf(v);
                fpd[rt][q] = fmaf(v, pw, fpd[rt][q]);
            }
        }
    }
#pragma unroll
    for (int rt = 0; rt < 2; ++rt)
#pragma unroll
        for (int q = 0; q < 4; ++q) {
            float d = fpd[rt][q];
#pragma unroll
            for (int m = 1; m < 16; m <<= 1) d += __shfl_xor(d, m);
            fpd[rt][q] = d;
        }
    float s0 = 0.f;
    if (col0 == 0) {
        float pb = projb[0];
#pragma unroll
        for (int rt = 0; rt < 2; ++rt)
#pragma unroll
            for (int q = 0; q < 4; ++q) {
                int row = rowblk + rt * 16 + (lane >> 4) * 4 + q;
                if (row < N) {
                    fp0[row] = fpd[rt][q] + pb;
                    s0 += fpd[rt][q];
                }
            }
    }
    s0 += __shfl_xor(s0, 16);
    s0 += __shfl_xor(s0, 32);
    if (lane == 0) bufA[w][0] = s0;
    __syncthreads();
    if (tid == 0) atomicAdd(msum, bufA[0][0] + bufA[1][0] + bufA[2][0] + bufA[3][0]);
}

// ---------------- degree histogram per (dest, source-window) ----------------
__global__ void k_deg(const int* __restrict__ ei, int* __restrict__ degw, int E, int wsz) {
    int e = blockIdx.x * 256 + threadIdx.x;
    if (e >= E) return;
    int r = ei[e], c = ei[E + e];
    atomicAdd(&degw[c * NWIN + r / wsz], 1);
}

// ---------------- dinv from summed window degrees ----------------
__global__ void k_dinv(const int* __restrict__ degw, float* __restrict__ dinv, int N) {
    int i = blockIdx.x * 256 + threadIdx.x;
    if (i >= N) return;
    int d = 0;
#pragma unroll
    for (int w = 0; w < NWIN; ++w) d += degw[i * NWIN + w];
    dinv[i] = rsqrtf((float)(d + 1));
}

// ---------------- exclusive scan of degw (M = N*NWIN entries) ----------------
__global__ void k_scan1(const int* __restrict__ degw, int* __restrict__ offsW,
                        int* __restrict__ bsum, int M) {
    __shared__ int lds[256];
    int tid = threadIdx.x;
    int base = blockIdx.x * 1024;
    int c[4], s = 0;
#pragma unroll
    for (int i = 0; i < 4; ++i) {
        int g = base + tid * 4 + i;
        c[i] = (g < M) ? degw[g] : 0;
        s += c[i];
    }
    lds[tid] = s;
    __syncthreads();
    for (int off = 1; off < 256; off <<= 1) {
        int add = (tid >= off) ? lds[tid - off] : 0;
        __syncthreads();
        lds[tid] += add;
        __syncthreads();
    }
    int run = lds[tid] - s;
#pragma unroll
    for (int i = 0; i < 4; ++i) {
        int g = base + tid * 4 + i;
        if (g < M) offsW[g] = run;
        run += c[i];
    }
    if (tid == 0) bsum[blockIdx.x] = lds[255];
}
__global__ void k_scan2(int* __restrict__ bsum, int nb) {
    if (blockIdx.x == 0 && threadIdx.x == 0) {
        int run = 0;
        for (int i = 0; i < nb; ++i) { int v = bsum[i]; bsum[i] = run; run += v; }
    }
}
__global__ void k_scan3(int* __restrict__ offsW, const int* __restrict__ bsum, int M, int E) {
    int g = blockIdx.x * 256 + threadIdx.x;
    if (g < M) offsW[g] += bsum[g >> 10];
    else if (g == M) offsW[M] = E;
}

// ---------------- CSR fill into (dest, window) buckets ----------------
__global__ void k_fill(const int* __restrict__ ei, const int* __restrict__ offsW,
                       int* __restrict__ cursorW, int2* __restrict__ edat,
                       const float* __restrict__ dinv, int E, int wsz) {
    int e = blockIdx.x * 256 + threadIdx.x;
    if (e >= E) return;
    int r = ei[e], c = ei[E + e];
    int b = c * NWIN + r / wsz;
    int p = offsW[b] + atomicAdd(&cursorW[b], 1);
    edat[p] = make_int2(r, __float_as_int(dinv[r] * dinv[c]));
}

// ---------------- one hop, source-windowed for L2 residency ----------------
// Each wave owns 16 nodes (acc in registers); outer loop over 8 source windows
// keeps the concurrent gather footprint at ~3.2MB -> XCD-local L2 hits.
__global__ __launch_bounds__(256) void k_hop(
        const ushort* __restrict__ xin, ushort* __restrict__ xout,
        const int* __restrict__ offsW, const int2* __restrict__ edat,
        const float* __restrict__ dinv,
        const float* __restrict__ projw, const float* __restrict__ projb,
        float* __restrict__ fpk, float* __restrict__ msum, int N) {
    int lane = threadIdx.x & 63;
    int gw = blockIdx.x * 4 + (threadIdx.x >> 6);
    int n0 = gw * 16;
    if (n0 >= N) return;
    const uint* xin2 = (const uint*)xin;

    float acc0[16], acc1[16];
#pragma unroll
    for (int i = 0; i < 16; ++i) {
        int nc = min(n0 + i, N - 1);
        float dn = dinv[nc];
        uint sv = xin2[(size_t)nc * 64 + lane];
        float ws = dn * dn;
        acc0[i] = ws * bflo(sv);
        acc1[i] = ws * bfhi(sv);
    }

#pragma unroll 1
    for (int w = 0; w < NWIN; ++w) {
#pragma unroll
        for (int i = 0; i < 16; ++i) {
            int nc = min(n0 + i, N - 1);
            int s = __builtin_amdgcn_readfirstlane(offsW[nc * NWIN + w]);
            int e = __builtin_amdgcn_readfirstlane(offsW[nc * NWIN + w + 1]);
            float a0 = acc0[i], a1 = acc1[i];
            int j = s;
            for (; j + 2 <= e; j += 2) {
                int2 e0 = edat[j];
                int2 e1 = edat[j + 1];
                uint x0 = xin2[(size_t)(uint)e0.x * 64 + lane];
                uint x1 = xin2[(size_t)(uint)e1.x * 64 + lane];
                float w0 = __int_as_float(e0.y);
                float w1 = __int_as_float(e1.y);
                a0 = fmaf(w0, bflo(x0), a0); a1 = fmaf(w0, bfhi(x0), a1);
                a0 = fmaf(w1, bflo(x1), a0); a1 = fmaf(w1, bfhi(x1), a1);
            }
            if (j < e) {
                int2 e0 = edat[j];
                uint x0 = xin2[(size_t)(uint)e0.x * 64 + lane];
                float w0 = __int_as_float(e0.y);
                a0 = fmaf(w0, bflo(x0), a0); a1 = fmaf(w0, bfhi(x0), a1);
            }
            acc0[i] = a0; acc1[i] = a1;
        }
    }

    float pw0 = projw[2 * lane], pw1 = projw[2 * lane + 1];
    float pb = projb[0];
    float ms = 0.f;
#pragma unroll
    for (int i = 0; i < 16; ++i) {
        int n = n0 + i;
        float dot = acc0[i] * pw0 + acc1[i] * pw1;
#pragma unroll
        for (int m = 1; m < 64; m <<= 1) dot += __shfl_xor(dot, m);
        if (n < N) {
            ((uint*)xout)[(size_t)n * 64 + lane] = packbf2(acc0[i], acc1[i]);
            if (lane == 0) { fpk[n] = dot + pb; ms += dot + pb; }
        }
    }
    if (lane == 0) atomicAdd(msum, ms);
}

// ---------------- share_w = l2norm(mean + hop_w) ----------------
__global__ void k_sharew(const float* __restrict__ msum, const float* __restrict__ hopw,
                         float* __restrict__ sharew, const float* __restrict__ projb, int N) {
    int k = threadIdx.x;
    float s = 0.f;
    if (k < KHOPS + 1) {
        s = msum[k] / (float)N + hopw[k];
        if (k == 0) s += projb[0];
    }
    float ss = s * s;
#pragma unroll
    for (int m = 1; m < 64; m <<= 1) ss += __shfl_xor(ss, m);
    float inv = 1.f / fmaxf(sqrtf(ss), 1e-12f);
    if (k < KHOPS + 1) sharew[k] = s * inv;
}

// ---------------- k_out: combine hops, tanh, MFMA W2, log_softmax ----------------
__global__ __launch_bounds__(256) void k_out(
                     const ushort* __restrict__ hops, const float* __restrict__ fp,
                     const float* __restrict__ sharew, const ushort* __restrict__ w2f,
                     const float* __restrict__ b2, float* __restrict__ out, int N) {
    __shared__ __align__(16) char As[16 * 256];
    int tid = threadIdx.x;
    int nloc = tid >> 4;
    int fg = tid & 15;
    int node = blockIdx.x * 16 + nloc;
    bool valid = node < N;
    int nodec = valid ? node : N - 1;
    const uint* hops2 = (const uint*)hops;

    float c[KHOPS + 1];
    float ss = 0.f;
#pragma unroll
    for (int k = 0; k <= KHOPS; ++k) {
        float f = fp[(size_t)k * N + nodec];
        c[k] = f;
        ss += f * f;
    }
    float inv = 1.f / fmaxf(sqrtf(ss), 1e-12f);
#pragma unroll
    for (int k = 0; k <= KHOPS; ++k)
        c[k] = valid ? (0.2f * sharew[k] + 0.8f * c[k] * inv) : 0.f;

    const uint* base = hops2 + (size_t)nodec * 64 + fg * 4;
    size_t kstr = (size_t)N * 64;
    float a[8];
#pragma unroll
    for (int j = 0; j < 8; ++j) a[j] = 0.f;
#pragma unroll
    for (int k = 0; k <= KHOPS; ++k) {
        uint4 v = *(const uint4*)(base + (size_t)k * kstr);
        float ck = c[k];
        a[0] = fmaf(ck, bflo(v.x), a[0]);
        a[1] = fmaf(ck, bfhi(v.x), a[1]);
        a[2] = fmaf(ck, bflo(v.y), a[2]);
        a[3] = fmaf(ck, bfhi(v.y), a[3]);
        a[4] = fmaf(ck, bflo(v.z), a[4]);
        a[5] = fmaf(ck, bfhi(v.z), a[5]);
        a[6] = fmaf(ck, bflo(v.w), a[6]);
        a[7] = fmaf(ck, bfhi(v.w), a[7]);
    }
    uint4 pk;
    pk.x = packbf2(tanhf(a[0]), tanhf(a[1]));
    pk.y = packbf2(tanhf(a[2]), tanhf(a[3]));
    pk.z = packbf2(tanhf(a[4]), tanhf(a[5]));
    pk.w = packbf2(tanhf(a[6]), tanhf(a[7]));
    {
        int slotbyte = fg * 16;
        int addr = nloc * 256 + (slotbyte ^ ((nloc & 15) << 4));
        *(uint4*)(As + addr) = pk;
    }
    __syncthreads();

    int w = tid >> 6, lane = tid & 63;
    floatx4 acc = (floatx4){0.f, 0.f, 0.f, 0.f};
    if (w < 3) {
        int r = lane & 15;
#pragma unroll
        for (int kk = 0; kk < 4; ++kk) {
            int slotbyte = kk * 64 + (lane >> 4) * 16;
            int addr = r * 256 + (slotbyte ^ ((r & 15) << 4));
            short8 af = *(const short8*)(As + addr);
            const short8 bf = *(const short8*)(w2f + (size_t)((kk * 3 + w) * 64 + lane) * 8);
            acc = __builtin_amdgcn_mfma_f32_16x16x32_bf16(af, bf, acc, 0, 0, 0);
        }
    }
    __syncthreads();

    float* Ls = (float*)As;
    if (w < 3) {
        int cls = w * 16 + (lane & 15);
        float bb = (cls < NC) ? b2[cls] : 0.f;
#pragma unroll
        for (int q = 0; q < 4; ++q) {
            int row = (lane >> 4) * 4 + q;
            Ls[row * 48 + cls] = acc[q] + bb;
        }
    }
    __syncthreads();

    int r2 = tid >> 4;
    int c16 = tid & 15;
    float v0 = Ls[r2 * 48 + c16];
    float v1 = Ls[r2 * 48 + 16 + c16];
    bool has2 = c16 < 8;
    float v2 = has2 ? Ls[r2 * 48 + 32 + c16] : -INFINITY;
    float lm = fmaxf(fmaxf(v0, v1), v2);
#pragma unroll
    for (int m = 1; m < 16; m <<= 1) lm = fmaxf(lm, __shfl_xor(lm, m));
    float se = expf(v0 - lm) + expf(v1 - lm) + (has2 ? expf(v2 - lm) : 0.f);
#pragma unroll
    for (int m = 1; m < 16; m <<= 1) se += __shfl_xor(se, m);
    float lse = lm + logf(se);
    int nodeo = blockIdx.x * 16 + r2;
    if (nodeo < N) {
        out[(size_t)nodeo * NC + c16] = v0 - lse;
        out[(size_t)nodeo * NC + 16 + c16] = v1 - lse;
        if (has2) out[(size_t)nodeo * NC + 32 + c16] = v2 - lse;
    }
}

// ---------------- launch ----------------
extern "C" void kernel_launch(void* const* d_in, const int* in_sizes, int n_in,
                              void* d_out, int out_size, void* d_ws, size_t ws_size,
                              hipStream_t stream) {
    const float* x     = (const float*)d_in[0];
    const int*   ei    = (const int*)d_in[1];
    const float* W1    = (const float*)d_in[2];
    const float* b1    = (const float*)d_in[3];
    const float* projw = (const float*)d_in[4];
    const float* projb = (const float*)d_in[5];
    const float* hopw  = (const float*)d_in[6];
    const float* W2    = (const float*)d_in[7];
    const float* b2    = (const float*)d_in[8];
    float* out = (float*)d_out;

    int N = in_sizes[0] / FIN;
    int E = in_sizes[1] / 2;
    int wsz = (N + NWIN - 1) / NWIN;
    int M = N * NWIN;

    char* p = (char*)d_ws;
    auto alloc = [&](size_t bytes) -> char* {
        char* r = p;
        p += (bytes + 255) & ~(size_t)255;
        return r;
    };
    ushort* hops    = (ushort*)alloc((size_t)(KHOPS + 1) * N * HF * 2);
    int*    degw    = (int*)alloc((size_t)M * 4);
    int*    cursorW = (int*)alloc((size_t)M * 4);   // adjacent to degw: one memset
    float*  dinv    = (float*)alloc((size_t)N * 4);
    int*    offsW   = (int*)alloc((size_t)(M + 1) * 4);
    int*    bsum    = (int*)alloc(4096);
    int2*   edat    = (int2*)alloc((size_t)E * 8);
    float*  fp      = (float*)alloc((size_t)(KHOPS + 1) * N * 4);
    float*  msum    = (float*)alloc(64);
    float*  sharew  = (float*)alloc(64);
    ushort* w1f     = (ushort*)alloc((size_t)FIN * HF * 2);
    ushort* w2f     = (ushort*)alloc((size_t)12 * 64 * 8 * 2);

    int nbE    = (E + 255) / 256;
    int nbM    = (M + 1023) / 1024;   // scan blocks over M entries

    size_t zlen = (size_t)((char*)cursorW - (char*)degw) + (size_t)M * 4;
    hipMemsetAsync(degw, 0, zlen, stream);
    hipMemsetAsync(msum, 0, 64, stream);

    k_w1frag<<<32, 256, 0, stream>>>(W1, w1f);
    k_w2frag<<<3, 256, 0, stream>>>(W2, w2f);
    k_gemm<<<(N + 127) / 128, 256, 0, stream>>>(x, w1f, b1, hops, projw, projb, fp, msum, N);

    k_deg<<<nbE, 256, 0, stream>>>(ei, degw, E, wsz);
    k_dinv<<<(N + 255) / 256, 256, 0, stream>>>(degw, dinv, N);
    k_scan1<<<nbM, 256, 0, stream>>>(degw, offsW, bsum, M);
    k_scan2<<<1, 64, 0, stream>>>(bsum, nbM);
    k_scan3<<<(M + 256) / 256, 256, 0, stream>>>(offsW, bsum, M, E);
    k_fill<<<nbE, 256, 0, stream>>>(ei, offsW, cursorW, edat, dinv, E, wsz);

    int nbHop = (N + 63) / 64;   // 4 waves/block, 16 nodes/wave
    for (int k = 1; k <= KHOPS; ++k) {
        const ushort* xin = hops + (size_t)(k - 1) * N * HF;
        ushort* xout      = hops + (size_t)k * N * HF;
        k_hop<<<nbHop, 256, 0, stream>>>(xin, xout, offsW, edat, dinv,
                                         projw, projb, fp + (size_t)k * N, msum + k, N);
    }

    k_sharew<<<1, 64, 0, stream>>>(msum, hopw, sharew, projb, N);
    k_out<<<(N + 15) / 16, 256, 0, stream>>>(hops, fp, sharew, w2f, b2, out, N);
}

// Round 9
// 963.098 us; speedup vs baseline: 3.0130x; 3.0071x over previous
//
#include <hip/hip_runtime.h>

typedef unsigned int uint;
typedef unsigned short ushort;

typedef short short8 __attribute__((ext_vector_type(8)));
typedef float floatx4 __attribute__((ext_vector_type(4)));
typedef uint uintx4 __attribute__((ext_vector_type(4)));

#define FIN 512
#define HF  128
#define NC  40
#define KHOPS 10

__device__ __forceinline__ ushort f2bf(float f) {
    uint u = __float_as_uint(f);
    uint r = (u + 0x7fffu + ((u >> 16) & 1u)) >> 16;
    return (ushort)r;
}
__device__ __forceinline__ float bflo(uint v) { return __uint_as_float(v << 16); }
__device__ __forceinline__ float bfhi(uint v) { return __uint_as_float(v & 0xffff0000u); }
__device__ __forceinline__ uint packbf2(float a, float b) {
    return (uint)f2bf(a) | ((uint)f2bf(b) << 16);
}
__device__ __forceinline__ uint cvtpk(float lo, float hi) {
    uint r;
    asm("v_cvt_pk_bf16_f32 %0, %1, %2" : "=v"(r) : "v"(lo), "v"(hi));
    return r;
}
__device__ __forceinline__ float selu_f(float v) {
    const float l = 1.0507009873554805f, a = 1.6732632423543772f;
    return v > 0.f ? l * v : l * a * (expf(v) - 1.f);
}

#define GLDS16(g, l)                                                        \
    __builtin_amdgcn_global_load_lds(                                       \
        (const __attribute__((address_space(1))) void*)(g),                 \
        (__attribute__((address_space(3))) void*)(l), 16, 0, 0)

// ---------------- W1 -> MFMA fragment layout (bf16) ----------------
__global__ void k_w1frag(const float* __restrict__ W1, ushort* __restrict__ w1f) {
    int id = blockIdx.x * 256 + threadIdx.x;
    if (id >= 16 * 8 * 64) return;
    int l = id & 63;
    int t = (id >> 6) & 7;
    int s = id >> 9;
    int row0 = s * 32 + (l >> 4) * 8;
    int col  = t * 16 + (l & 15);
    ushort* dst = w1f + (size_t)id * 8;
#pragma unroll
    for (int i = 0; i < 8; ++i)
        dst[i] = f2bf(W1[(row0 + i) * HF + col]);
}

// ---------------- W2 -> MFMA fragment layout (bf16, 48-col padded) ----------------
__global__ void k_w2frag(const float* __restrict__ W2, ushort* __restrict__ w2f) {
    int id = blockIdx.x * 256 + threadIdx.x;
    if (id >= 12 * 64) return;
    int l = id & 63;
    int tile = id >> 6;
    int kk = tile / 3, t = tile % 3;
    int row0 = kk * 32 + (l >> 4) * 8;
    int col  = t * 16 + (l & 15);
    ushort* dst = w2f + (size_t)id * 8;
#pragma unroll
    for (int i = 0; i < 8; ++i)
        dst[i] = (col < NC) ? f2bf(W2[(row0 + i) * NC + col]) : (ushort)0;
}

// ---------------- h = selu(x@W1+b1) -> hops[0] (bf16), fused fp0 + msum[0] ----
__global__ __launch_bounds__(256) void k_gemm(
        const float* __restrict__ x, const ushort* __restrict__ w1f,
        const float* __restrict__ b1, ushort* __restrict__ h,
        const float* __restrict__ projw, const float* __restrict__ projb,
        float* __restrict__ fp0, float* __restrict__ msum, int N) {
    __shared__ __align__(16) float bufA[4][32 * 32];
    __shared__ __align__(16) float bufB[4][32 * 32];
    int tid = threadIdx.x;
    int lane = tid & 63, w = tid >> 6;
    int rowblk = blockIdx.x * 128 + w * 32;

    int srl = lane >> 3;
    int ssl = lane & 7;
    int srcoff = ((ssl ^ srl) << 2);
    float* bA = bufA[w];
    float* bB = bufB[w];

    floatx4 acc[2][8];
#pragma unroll
    for (int rt = 0; rt < 2; ++rt)
#pragma unroll
        for (int t = 0; t < 8; ++t) acc[rt][t] = (floatx4){0.f, 0.f, 0.f, 0.f};

    short8 bE[8], bO[8];

    auto STAGE = [&](float* lbuf, int kk) {
        int k0 = kk * 32;
#pragma unroll
        for (int i = 0; i < 4; ++i) {
            int row = rowblk + i * 8 + srl;
            const float* g = x + (size_t)min(row, N - 1) * FIN + k0 + srcoff;
            GLDS16(g, lbuf + i * 256);
        }
    };
    auto LOADB = [&](short8* bb, int kk) {
        const ushort* wp = w1f + ((size_t)(kk * 8) * 64 + lane) * 8;
#pragma unroll
        for (int t = 0; t < 8; ++t) bb[t] = *(const short8*)(wp + (size_t)t * 512);
    };

    int rl16 = lane & 15, cq = lane >> 4;
    int lo_sl = ((2 * cq) ^ (rl16 & 7)) << 4;
    int hi_sl = ((2 * cq + 1) ^ (rl16 & 7)) << 4;

    auto COMPUTE = [&](const float* lbuf, short8* bb) {
#pragma unroll
        for (int rt = 0; rt < 2; ++rt) {
            const char* rbase = (const char*)lbuf + (rt * 16 + rl16) * 128;
            float4 lo = *(const float4*)(rbase + lo_sl);
            float4 hi = *(const float4*)(rbase + hi_sl);
            uintx4 pa;
            pa.x = cvtpk(lo.x, lo.y); pa.y = cvtpk(lo.z, lo.w);
            pa.z = cvtpk(hi.x, hi.y); pa.w = cvtpk(hi.z, hi.w);
            short8 af = __builtin_bit_cast(short8, pa);
#pragma unroll
            for (int t = 0; t < 8; ++t)
                acc[rt][t] = __builtin_amdgcn_mfma_f32_16x16x32_bf16(af, bb[t], acc[rt][t], 0, 0, 0);
        }
    };

    STAGE(bA, 0);
    LOADB(bE, 0);
#pragma unroll 1
    for (int kk = 0; kk < 16; kk += 2) {
        asm volatile("s_waitcnt lgkmcnt(0)" ::: "memory");
        __builtin_amdgcn_sched_barrier(0);
        STAGE(bB, kk + 1);
        LOADB(bO, kk + 1);
        asm volatile("s_waitcnt vmcnt(12)" ::: "memory");
        __builtin_amdgcn_sched_barrier(0);
        COMPUTE(bA, bE);
        asm volatile("s_waitcnt lgkmcnt(0)" ::: "memory");
        __builtin_amdgcn_sched_barrier(0);
        if (kk + 2 < 16) {
            STAGE(bA, kk + 2);
            LOADB(bE, kk + 2);
            asm volatile("s_waitcnt vmcnt(12)" ::: "memory");
        } else {
            asm volatile("s_waitcnt vmcnt(0)" ::: "memory");
        }
        __builtin_amdgcn_sched_barrier(0);
        COMPUTE(bB, bO);
    }

    int col0 = lane & 15;
    float fpd[2][4];
#pragma unroll
    for (int rt = 0; rt < 2; ++rt)
#pragma unroll
        for (int q = 0; q < 4; ++q) fpd[rt][q] = 0.f;
#pragma unroll
    for (int t = 0; t < 8; ++t) {
        int col = t * 16 + col0;
        float bias = b1[col];
        float pw = projw[col];
#pragma unroll
        for (int rt = 0; rt < 2; ++rt) {
#pragma unroll
            for (int q = 0; q < 4; ++q) {
                int row = rowblk + rt * 16 + (lane >> 4) * 4 + q;
                float v = selu_f(acc[rt][t][q] + bias);
                if (row < N) h[(size_t)row * HF + col] = f2bf(v);
                fpd[rt][q] = fmaf(v, pw, fpd[rt][q]);
            }
        }
    }
#pragma unroll
    for (int rt = 0; rt < 2; ++rt)
#pragma unroll
        for (int q = 0; q < 4; ++q) {
            float d = fpd[rt][q];
#pragma unroll
            for (int m = 1; m < 16; m <<= 1) d += __shfl_xor(d, m);
            fpd[rt][q] = d;
        }
    float s0 = 0.f;
    if (col0 == 0) {
        float pb = projb[0];
#pragma unroll
        for (int rt = 0; rt < 2; ++rt)
#pragma unroll
            for (int q = 0; q < 4; ++q) {
                int row = rowblk + rt * 16 + (lane >> 4) * 4 + q;
                if (row < N) {
                    fp0[row] = fpd[rt][q] + pb;
                    s0 += fpd[rt][q];   // pb added once per node in k_sharew
                }
            }
    }
    s0 += __shfl_xor(s0, 16);
    s0 += __shfl_xor(s0, 32);
    if (lane == 0) bufA[w][0] = s0;
    __syncthreads();
    if (tid == 0) atomicAdd(msum, bufA[0][0] + bufA[1][0] + bufA[2][0] + bufA[3][0]);
}

// ---------------- degree (real edges only; self handled as +1) ----------------
__global__ void k_deg(const int* __restrict__ ei, int* __restrict__ deg, int E) {
    int e = blockIdx.x * 256 + threadIdx.x;
    if (e < E) atomicAdd(&deg[ei[E + e]], 1);
}

// ---------------- exclusive scan of deg -> offsets, fused dinv ----------------
__global__ void k_scan1(const int* __restrict__ deg, int* __restrict__ offs,
                        int* __restrict__ bsum, float* __restrict__ dinv, int N) {
    __shared__ int lds[256];
    int tid = threadIdx.x;
    int base = blockIdx.x * 1024;
    int c[4], s = 0;
#pragma unroll
    for (int i = 0; i < 4; ++i) {
        int g = base + tid * 4 + i;
        int dv = (g < N) ? deg[g] : 0;
        if (g < N) dinv[g] = rsqrtf((float)(dv + 1));
        c[i] = dv;
        s += dv;
    }
    lds[tid] = s;
    __syncthreads();
    for (int off = 1; off < 256; off <<= 1) {
        int add = (tid >= off) ? lds[tid - off] : 0;
        __syncthreads();
        lds[tid] += add;
        __syncthreads();
    }
    int run = lds[tid] - s;
#pragma unroll
    for (int i = 0; i < 4; ++i) {
        int g = base + tid * 4 + i;
        if (g < N) offs[g] = run;
        run += c[i];
    }
    if (tid == 0) bsum[blockIdx.x] = lds[255];
}
__global__ void k_scan2(int* __restrict__ bsum, int nb) {
    if (blockIdx.x == 0 && threadIdx.x == 0) {
        int run = 0;
        for (int i = 0; i < nb; ++i) { int v = bsum[i]; bsum[i] = run; run += v; }
    }
}
__global__ void k_scan3(int* __restrict__ offs, const int* __restrict__ bsum, int N, int E) {
    int g = blockIdx.x * 256 + threadIdx.x;
    if (g < N) offs[g] += bsum[g >> 10];
    else if (g == N) offs[N] = E;
}

// ---------------- CSR fill: edat = {src, bits(dinv_r*dinv_c)} ----------------
__global__ void k_fill(const int* __restrict__ ei, const int* __restrict__ offs,
                       int* __restrict__ cursor, int2* __restrict__ edat,
                       const float* __restrict__ dinv, int E) {
    int e = blockIdx.x * 256 + threadIdx.x;
    if (e >= E) return;
    int r = ei[e], c = ei[E + e];
    int p = offs[c] + atomicAdd(&cursor[c], 1);
    edat[p] = make_int2(r, __float_as_int(dinv[r] * dinv[c]));
}

// ---------------- one hop: xn = A_hat @ xc, 16-deep gather groups ----
__global__ __launch_bounds__(256) void k_hop(
                      const ushort* __restrict__ xin, ushort* __restrict__ xout,
                      const int* __restrict__ offs, const int2* __restrict__ edat,
                      const float* __restrict__ dinv,
                      const float* __restrict__ projw, const float* __restrict__ projb,
                      float* __restrict__ fpk, int N) {
    int wid = (blockIdx.x * blockDim.x + threadIdx.x) >> 6;
    int lane = threadIdx.x & 63;
    if (wid >= N) return;
    const uint* xin2 = (const uint*)xin;
    float dn = dinv[wid];
    uint sv = xin2[(size_t)wid * 64 + lane];
    float wself = dn * dn;
    float acc0 = wself * bflo(sv);
    float acc1 = wself * bfhi(sv);
    int s = offs[wid], e = offs[wid + 1];
    for (int base = s; base < e; base += 64) {
        int idx = base + lane;
        int idxc = min(idx, e - 1);
        int2 ed = edat[idxc];
        int src = ed.x;
        float ew = (idx < e) ? __int_as_float(ed.y) : 0.f;
        int cnt = min(64, e - base);
        int groups = (cnt + 15) >> 4;
        for (int g = 0; g < groups; ++g) {
            int j = g * 16;
            uint xv[16];
            float wv[16];
#pragma unroll
            for (int u = 0; u < 16; ++u) {
                int sj = __builtin_amdgcn_readlane(src, j + u);
                wv[u] = __int_as_float(__builtin_amdgcn_readlane(__float_as_int(ew), j + u));
                xv[u] = xin2[(size_t)(uint)sj * 64 + lane];
            }
#pragma unroll
            for (int u = 0; u < 16; ++u) {
                acc0 = fmaf(wv[u], bflo(xv[u]), acc0);
                acc1 = fmaf(wv[u], bfhi(xv[u]), acc1);
            }
        }
    }
    ((uint*)xout)[(size_t)wid * 64 + lane] = packbf2(acc0, acc1);
    float dot = acc0 * projw[2 * lane] + acc1 * projw[2 * lane + 1];
#pragma unroll
    for (int m = 1; m < 64; m <<= 1) dot += __shfl_xor(dot, m);
    if (lane == 0) fpk[wid] = dot + projb[0];
}

// ---------------- mean of feature_pool over nodes (k = 1..KHOPS) ----------------
__global__ void k_msum(const float* __restrict__ fp, float* __restrict__ msum, int N) {
    int k = blockIdx.y + 1;
    int i = blockIdx.x * 256 + threadIdx.x;
    int tid = threadIdx.x;
    float v = (i < N) ? fp[(size_t)k * N + i] : 0.f;
#pragma unroll
    for (int m = 1; m < 64; m <<= 1) v += __shfl_xor(v, m);
    __shared__ float ws4[4];
    if ((tid & 63) == 0) ws4[tid >> 6] = v;
    __syncthreads();
    if (tid == 0) atomicAdd(&msum[k], ws4[0] + ws4[1] + ws4[2] + ws4[3]);
}

// ---------------- share_w = l2norm(mean + hop_w) ----------------
__global__ void k_sharew(const float* __restrict__ msum, const float* __restrict__ hopw,
                         float* __restrict__ sharew, const float* __restrict__ projb, int N) {
    int k = threadIdx.x;
    float s = 0.f;
    if (k < KHOPS + 1) {
        s = msum[k] / (float)N + hopw[k];
        if (k == 0) s += projb[0];   // msum[0] accumulated without pb
    }
    float ss = s * s;
#pragma unroll
    for (int m = 1; m < 64; m <<= 1) ss += __shfl_xor(ss, m);
    float inv = 1.f / fmaxf(sqrtf(ss), 1e-12f);
    if (k < KHOPS + 1) sharew[k] = s * inv;
}

// ---------------- k_out: 16 nodes/block; single-pass combine (16B/thread),
//                  tanh -> LDS, MFMA K=128 N=48, log_softmax ----------------
__global__ __launch_bounds__(256) void k_out(
                     const ushort* __restrict__ hops, const float* __restrict__ fp,
                     const float* __restrict__ sharew, const ushort* __restrict__ w2f,
                     const float* __restrict__ b2, float* __restrict__ out, int N) {
    __shared__ __align__(16) char As[16 * 256];
    int tid = threadIdx.x;
    int nloc = tid >> 4;
    int fg = tid & 15;
    int node = blockIdx.x * 16 + nloc;
    bool valid = node < N;
    int nodec = valid ? node : N - 1;
    const uint* hops2 = (const uint*)hops;

    float c[KHOPS + 1];
    float ss = 0.f;
#pragma unroll
    for (int k = 0; k <= KHOPS; ++k) {
        float f = fp[(size_t)k * N + nodec];
        c[k] = f;
        ss += f * f;
    }
    float inv = 1.f / fmaxf(sqrtf(ss), 1e-12f);
#pragma unroll
    for (int k = 0; k <= KHOPS; ++k)
        c[k] = valid ? (0.2f * sharew[k] + 0.8f * c[k] * inv) : 0.f;

    const uint* base = hops2 + (size_t)nodec * 64 + fg * 4;
    size_t kstr = (size_t)N * 64;
    float a[8];
#pragma unroll
    for (int j = 0; j < 8; ++j) a[j] = 0.f;
#pragma unroll
    for (int k = 0; k <= KHOPS; ++k) {
        uint4 v = *(const uint4*)(base + (size_t)k * kstr);
        float ck = c[k];
        a[0] = fmaf(ck, bflo(v.x), a[0]);
        a[1] = fmaf(ck, bfhi(v.x), a[1]);
        a[2] = fmaf(ck, bflo(v.y), a[2]);
        a[3] = fmaf(ck, bfhi(v.y), a[3]);
        a[4] = fmaf(ck, bflo(v.z), a[4]);
        a[5] = fmaf(ck, bfhi(v.z), a[5]);
        a[6] = fmaf(ck, bflo(v.w), a[6]);
        a[7] = fmaf(ck, bfhi(v.w), a[7]);
    }
    uint4 pk;
    pk.x = packbf2(tanhf(a[0]), tanhf(a[1]));
    pk.y = packbf2(tanhf(a[2]), tanhf(a[3]));
    pk.z = packbf2(tanhf(a[4]), tanhf(a[5]));
    pk.w = packbf2(tanhf(a[6]), tanhf(a[7]));
    {
        int slotbyte = fg * 16;
        int addr = nloc * 256 + (slotbyte ^ ((nloc & 15) << 4));
        *(uint4*)(As + addr) = pk;
    }
    __syncthreads();

    int w = tid >> 6, lane = tid & 63;
    floatx4 acc = (floatx4){0.f, 0.f, 0.f, 0.f};
    if (w < 3) {
        int r = lane & 15;
#pragma unroll
        for (int kk = 0; kk < 4; ++kk) {
            int slotbyte = kk * 64 + (lane >> 4) * 16;
            int addr = r * 256 + (slotbyte ^ ((r & 15) << 4));
            short8 af = *(const short8*)(As + addr);
            const short8 bf = *(const short8*)(w2f + (size_t)((kk * 3 + w) * 64 + lane) * 8);
            acc = __builtin_amdgcn_mfma_f32_16x16x32_bf16(af, bf, acc, 0, 0, 0);
        }
    }
    __syncthreads();

    float* Ls = (float*)As;
    if (w < 3) {
        int cls = w * 16 + (lane & 15);
        float bb = (cls < NC) ? b2[cls] : 0.f;
#pragma unroll
        for (int q = 0; q < 4; ++q) {
            int row = (lane >> 4) * 4 + q;
            Ls[row * 48 + cls] = acc[q] + bb;
        }
    }
    __syncthreads();

    int r2 = tid >> 4;
    int c16 = tid & 15;
    float v0 = Ls[r2 * 48 + c16];
    float v1 = Ls[r2 * 48 + 16 + c16];
    bool has2 = c16 < 8;
    float v2 = has2 ? Ls[r2 * 48 + 32 + c16] : -INFINITY;
    float lm = fmaxf(fmaxf(v0, v1), v2);
#pragma unroll
    for (int m = 1; m < 16; m <<= 1) lm = fmaxf(lm, __shfl_xor(lm, m));
    float se = expf(v0 - lm) + expf(v1 - lm) + (has2 ? expf(v2 - lm) : 0.f);
#pragma unroll
    for (int m = 1; m < 16; m <<= 1) se += __shfl_xor(se, m);
    float lse = lm + logf(se);
    int nodeo = blockIdx.x * 16 + r2;
    if (nodeo < N) {
        out[(size_t)nodeo * NC + c16] = v0 - lse;
        out[(size_t)nodeo * NC + 16 + c16] = v1 - lse;
        if (has2) out[(size_t)nodeo * NC + 32 + c16] = v2 - lse;
    }
}

// ---------------- launch ----------------
extern "C" void kernel_launch(void* const* d_in, const int* in_sizes, int n_in,
                              void* d_out, int out_size, void* d_ws, size_t ws_size,
                              hipStream_t stream) {
    const float* x     = (const float*)d_in[0];
    const int*   ei    = (const int*)d_in[1];
    const float* W1    = (const float*)d_in[2];
    const float* b1    = (const float*)d_in[3];
    const float* projw = (const float*)d_in[4];
    const float* projb = (const float*)d_in[5];
    const float* hopw  = (const float*)d_in[6];
    const float* W2    = (const float*)d_in[7];
    const float* b2    = (const float*)d_in[8];
    float* out = (float*)d_out;

    int N = in_sizes[0] / FIN;
    int E = in_sizes[1] / 2;

    char* p = (char*)d_ws;
    auto alloc = [&](size_t bytes) -> char* {
        char* r = p;
        p += (bytes + 255) & ~(size_t)255;
        return r;
    };
    ushort* hops   = (ushort*)alloc((size_t)(KHOPS + 1) * N * HF * 2);
    int*    deg    = (int*)alloc((size_t)N * 4);
    int*    cursor = (int*)alloc((size_t)N * 4);   // adjacent to deg: one memset covers both
    float*  dinv   = (float*)alloc((size_t)N * 4);
    int*    offs   = (int*)alloc((size_t)(N + 1) * 4);
    int*    bsum   = (int*)alloc(4096);
    int2*   edat   = (int2*)alloc((size_t)E * 8);
    float*  fp     = (float*)alloc((size_t)(KHOPS + 1) * N * 4);
    float*  msum   = (float*)alloc(64);
    float*  sharew = (float*)alloc(64);
    ushort* w1f    = (ushort*)alloc((size_t)FIN * HF * 2);
    ushort* w2f    = (ushort*)alloc((size_t)12 * 64 * 8 * 2);

    int nb256N = (N + 255) / 256;
    int nbE    = (E + 255) / 256;
    int nbWave = (N + 3) / 4;
    int nb1024 = (N + 1023) / 1024;

    size_t zlen = (size_t)((char*)cursor - (char*)deg) + (size_t)N * 4;
    hipMemsetAsync(deg, 0, zlen, stream);
    hipMemsetAsync(msum, 0, 64, stream);

    k_w1frag<<<32, 256, 0, stream>>>(W1, w1f);
    k_w2frag<<<3, 256, 0, stream>>>(W2, w2f);
    k_gemm<<<(N + 127) / 128, 256, 0, stream>>>(x, w1f, b1, hops, projw, projb, fp, msum, N);

    k_deg<<<nbE, 256, 0, stream>>>(ei, deg, E);
    k_scan1<<<nb1024, 256, 0, stream>>>(deg, offs, bsum, dinv, N);
    k_scan2<<<1, 64, 0, stream>>>(bsum, nb1024);
    k_scan3<<<(N + 256) / 256, 256, 0, stream>>>(offs, bsum, N, E);
    k_fill<<<nbE, 256, 0, stream>>>(ei, offs, cursor, edat, dinv, E);

    for (int k = 1; k <= KHOPS; ++k) {
        const ushort* xin = hops + (size_t)(k - 1) * N * HF;
        ushort* xout      = hops + (size_t)k * N * HF;
        k_hop<<<nbWave, 256, 0, stream>>>(xin, xout, offs, edat, dinv,
                                          projw, projb, fp + (size_t)k * N, N);
    }

    dim3 gm(nb256N, KHOPS);
    k_msum<<<gm, 256, 0, stream>>>(fp, msum, N);
    k_sharew<<<1, 64, 0, stream>>>(msum, hopw, sharew, projb, N);

    k_out<<<(N + 15) / 16, 256, 0, stream>>>(hops, fp, sharew, w2f, b2, out, N);
}